// Round 1
// baseline (1176.745 us; speedup 1.0000x reference)
//
#include <hip/hip_runtime.h>
#include <hip/hip_bf16.h>

#define BATCH 16
#define D_OUT 1024
#define D_HID 512
#define N0 9216      // 32*32*9
#define N1 4608      // 16*32*9
#define D_FLT 13824

__device__ __forceinline__ float lrelu(float x) { return x >= 0.f ? x : 0.2f * x; }

// out[b][j] = act(sum_k in[b][k] * W[j][k] + bias[j]); one wave per output.
template<int K, bool ACT>
__global__ void fc_kernel(const float* __restrict__ in, const float* __restrict__ W,
                          const float* __restrict__ bias, float* __restrict__ out) {
  int wid = (blockIdx.x * blockDim.x + threadIdx.x) >> 6;
  int lane = threadIdx.x & 63;
  int b = wid >> 9;          // JD = 512
  int j = wid & 511;
  float s = 0.f;
  for (int k = lane; k < K; k += 64) s += in[b * K + k] * W[j * K + k];
  #pragma unroll
  for (int off = 32; off; off >>= 1) s += __shfl_xor(s, off);
  if (lane == 0) {
    float v = s + bias[j];
    out[b * 512 + j] = ACT ? lrelu(v) : v;
  }
}

// weights[b][j] = sum_k h2[b][k] * W3[j][k] + b3[j]; wave per j, all 16 b at once.
__global__ void fc3_kernel(const float* __restrict__ h2, const float* __restrict__ W3,
                           const float* __restrict__ b3, float* __restrict__ wts) {
  __shared__ float hs[BATCH * D_HID];   // 32 KB
  int tid = threadIdx.x;
  for (int i = tid; i < BATCH * D_HID; i += 256) hs[i] = h2[i];
  __syncthreads();
  int w = tid >> 6, lane = tid & 63;
  int j = blockIdx.x * 4 + w;
  float acc[BATCH];
  #pragma unroll
  for (int b = 0; b < BATCH; ++b) acc[b] = 0.f;
  for (int k = lane; k < D_HID; k += 64) {
    float wv = W3[(size_t)j * D_HID + k];
    #pragma unroll
    for (int b = 0; b < BATCH; ++b) acc[b] += wv * hs[b * D_HID + k];
  }
  #pragma unroll
  for (int b = 0; b < BATCH; ++b) {
    #pragma unroll
    for (int off = 32; off; off >>= 1) acc[b] += __shfl_xor(acc[b], off);
  }
  if (lane == 0) {
    float bb = b3[j];
    #pragma unroll
    for (int b = 0; b < BATCH; ++b) wts[(size_t)b * D_FLT + j] = acc[b] + bb;
  }
}

// Fused conv1(32->32, 3x3, lrelu) + conv2(32->16, 3x3) per (batch, 16x16 tile).
// LDS: tex tile 20x20x32, inter 18x18x32 (row stride 20), filters (row stride 289).
__global__ __launch_bounds__(256) void conv_fused(const float* __restrict__ tex,
                                                  const float* __restrict__ wts,
                                                  float* __restrict__ out) {
  extern __shared__ float sm[];
  float* texs  = sm;                 // 32*400 = 12800
  float* inter = texs + 12800;       // 32*360 = 11520 (18 rows x stride 20)
  float* fw0   = inter + 11520;      // 32*289 = 9248
  float* fw1   = fw0 + 9248;         // 16*289 = 4624
  int tid = threadIdx.x;
  int tx0 = blockIdx.x * 16, ty0 = blockIdx.y * 16, b = blockIdx.z;
  const float* wb = wts + (size_t)b * D_FLT;

  // filters into LDS (padded stride 289 -> bank-spread per-co reads)
  for (int i = tid; i < 32 * 288; i += 256) { int co = i / 288, m = i - co * 288; fw0[co * 289 + m] = wb[i]; }
  for (int i = tid; i < 16 * 288; i += 256) { int co = i / 288, m = i - co * 288; fw1[co * 289 + m] = wb[N0 + i]; }
  // tex tile rows ty0-2..ty0+17, cols tx0-2..tx0+17, OOB -> 0 (conv1 zero pad)
  for (int i = tid; i < 32 * 400; i += 256) {
    int ci = i / 400, r = i - ci * 400;
    int ry = r / 20, rx = r - ry * 20;
    int gy = ty0 - 2 + ry, gx = tx0 - 2 + rx;
    float v = 0.f;
    if (gy >= 0 && gy < 256 && gx >= 0 && gx < 256) v = tex[ci * 65536 + gy * 256 + gx];
    texs[i] = v;
  }
  __syncthreads();

  // conv1 -> inter[co][iy][ix], global pos (ty0-1+iy, tx0-1+ix); lanes share iy -> tex row broadcast
  for (int t = tid; t < 576; t += 256) {
    int iy = t >> 5, co = t & 31;
    float acc[18];
    #pragma unroll
    for (int i = 0; i < 18; ++i) acc[i] = 0.f;
    for (int ci = 0; ci < 32; ++ci) {
      const float* wr = &fw0[co * 289 + ci * 9];
      float w[9];
      #pragma unroll
      for (int q = 0; q < 9; ++q) w[q] = wr[q];
      #pragma unroll
      for (int ky = 0; ky < 3; ++ky) {
        const float4* trow = (const float4*)&texs[ci * 400 + (iy + ky) * 20];
        float tr[20];
        #pragma unroll
        for (int q = 0; q < 5; ++q) { float4 v = trow[q]; tr[4*q]=v.x; tr[4*q+1]=v.y; tr[4*q+2]=v.z; tr[4*q+3]=v.w; }
        #pragma unroll
        for (int kx = 0; kx < 3; ++kx) {
          float wv = w[ky * 3 + kx];
          #pragma unroll
          for (int ix = 0; ix < 18; ++ix) acc[ix] += tr[ix + kx] * wv;
        }
      }
    }
    int gy = ty0 - 1 + iy;
    bool rok = (gy >= 0 && gy < 256);
    float* dst = &inter[co * 360 + iy * 20];
    #pragma unroll
    for (int ix = 0; ix < 18; ++ix) {
      int gx = tx0 - 1 + ix;
      float v = lrelu(acc[ix]);
      dst[ix] = (rok && gx >= 0 && gx < 256) ? v : 0.f;  // conv2 pads with ZEROS
    }
  }
  __syncthreads();

  // conv2: one thread per (oy, co); lanes share oy -> inter row broadcast
  {
    int oy = tid >> 4, co = tid & 15;
    float acc[16];
    #pragma unroll
    for (int i = 0; i < 16; ++i) acc[i] = 0.f;
    for (int ci = 0; ci < 32; ++ci) {
      const float* wr = &fw1[co * 289 + ci * 9];
      float w[9];
      #pragma unroll
      for (int q = 0; q < 9; ++q) w[q] = wr[q];
      #pragma unroll
      for (int ky = 0; ky < 3; ++ky) {
        const float4* trow = (const float4*)&inter[ci * 360 + (oy + ky) * 20];
        float tr[20];
        #pragma unroll
        for (int q = 0; q < 5; ++q) { float4 v = trow[q]; tr[4*q]=v.x; tr[4*q+1]=v.y; tr[4*q+2]=v.z; tr[4*q+3]=v.w; }
        #pragma unroll
        for (int kx = 0; kx < 3; ++kx) {
          float wv = w[ky * 3 + kx];
          #pragma unroll
          for (int ox = 0; ox < 16; ++ox) acc[ox] += tr[ox + kx] * wv;
        }
      }
    }
    float* op = out + ((size_t)(b * 16 + co) * 256 + (ty0 + oy)) * 256 + tx0;
    #pragma unroll
    for (int ox = 0; ox < 16; ++ox) op[ox] = acc[ox];
  }
}

extern "C" void kernel_launch(void* const* d_in, const int* in_sizes, int n_in,
                              void* d_out, int out_size, void* d_ws, size_t ws_size,
                              hipStream_t stream) {
  const float* z   = (const float*)d_in[0];
  const float* tex = (const float*)d_in[1];
  const float* W1  = (const float*)d_in[2];
  const float* b1  = (const float*)d_in[3];
  const float* W2  = (const float*)d_in[4];
  const float* b2  = (const float*)d_in[5];
  const float* W3  = (const float*)d_in[6];
  const float* b3  = (const float*)d_in[7];
  float* out = (float*)d_out;
  float* ws  = (float*)d_ws;
  float* h1  = ws;                 // 16*512
  float* h2  = ws + 8192;          // 16*512
  float* wts = ws + 16384;         // 16*13824

  fc_kernel<1024, true><<<2048, 256, 0, stream>>>(z, W1, b1, h1);
  fc_kernel<512,  true><<<2048, 256, 0, stream>>>(h1, W2, b2, h2);
  fc3_kernel<<<D_FLT / 4, 256, 0, stream>>>(h2, W3, b3, wts);

  dim3 grid(16, 16, BATCH);
  size_t lds_bytes = (size_t)(12800 + 11520 + 9248 + 4624) * sizeof(float);  // 152768
  conv_fused<<<grid, 256, lds_bytes, stream>>>(tex, wts, out);
}

// Round 3
// 129.465 us; speedup vs baseline: 9.0893x; 9.0893x over previous
//
#include <hip/hip_runtime.h>
#include <hip/hip_bf16.h>

#define BATCH 16
#define D_OUT 1024
#define D_HID 512
#define D_FLT 13824
#define N0Q 9216
#define TW 14
#define TH 16

typedef __attribute__((ext_vector_type(8))) short bf16x8;
typedef __attribute__((ext_vector_type(4))) float f32x4;

__device__ __forceinline__ float lrelu(float x) { return x >= 0.f ? x : 0.2f * x; }
__device__ __forceinline__ ushort f2bf(float x) {
  unsigned u = __float_as_uint(x);
  u += 0x7FFFu + ((u >> 16) & 1u);
  return (ushort)(u >> 16);
}

// out[b][j] = act(sum_k in[b][k] * W[j][k] + bias[j]); one wave per output.
template<int K, bool ACT>
__global__ void fc_kernel(const float* __restrict__ in, const float* __restrict__ W,
                          const float* __restrict__ bias, float* __restrict__ out) {
  int wid = (blockIdx.x * blockDim.x + threadIdx.x) >> 6;
  int lane = threadIdx.x & 63;
  int b = wid >> 9;
  int j = wid & 511;
  float s = 0.f;
  for (int k = lane; k < K; k += 64) s += in[b * K + k] * W[j * K + k];
  #pragma unroll
  for (int off = 32; off; off >>= 1) s += __shfl_xor(s, off);
  if (lane == 0) {
    float v = s + bias[j];
    out[b * 512 + j] = ACT ? lrelu(v) : v;
  }
}

// fc3: wave per j, all 16 batches; writes bf16 filters PERMUTED to
// conv layout: flt0 -> [kpos][co32][ci32], flt1 -> 9216 + [kpos][co16][ci32].
__global__ void fc3_kernel(const float* __restrict__ h2, const float* __restrict__ W3,
                           const float* __restrict__ b3, ushort* __restrict__ wbf) {
  __shared__ float hs[BATCH * D_HID];
  int tid = threadIdx.x;
  for (int i = tid; i < BATCH * D_HID; i += 256) hs[i] = h2[i];
  __syncthreads();
  int w = tid >> 6, lane = tid & 63;
  int j = blockIdx.x * 4 + w;
  float acc[BATCH];
  #pragma unroll
  for (int b = 0; b < BATCH; ++b) acc[b] = 0.f;
  for (int k = lane; k < D_HID; k += 64) {
    float wv = W3[(size_t)j * D_HID + k];
    #pragma unroll
    for (int b = 0; b < BATCH; ++b) acc[b] += wv * hs[b * D_HID + k];
  }
  #pragma unroll
  for (int b = 0; b < BATCH; ++b) {
    #pragma unroll
    for (int off = 32; off; off >>= 1) acc[b] += __shfl_xor(acc[b], off);
  }
  if (lane == 0) {
    float bb = b3[j];
    int dst;
    if (j < N0Q) {
      int co = j / 288, rem = j - co * 288;
      int ci = rem / 9, kp = rem - ci * 9;
      dst = kp * 1024 + co * 32 + ci;
    } else {
      int t = j - N0Q;
      int co = t / 288, rem = t - co * 288;
      int ci = rem / 9, kp = rem - ci * 9;
      dst = N0Q + kp * 512 + co * 32 + ci;
    }
    #pragma unroll
    for (int b = 0; b < BATCH; ++b) wbf[(size_t)b * D_FLT + dst] = f2bf(acc[b] + bb);
  }
}

// tex fp32 [32][256][256] -> bf16 pixel-major [256*256][32]
__global__ void tex_to_bf16(const float* __restrict__ tex, ushort* __restrict__ texT) {
  int p = blockIdx.x * 256 + threadIdx.x;
  unsigned pk[16];
  #pragma unroll
  for (int i = 0; i < 16; ++i) {
    ushort lo = f2bf(tex[(2 * i) * 65536 + p]);
    ushort hi = f2bf(tex[(2 * i + 1) * 65536 + p]);
    pk[i] = (unsigned)lo | ((unsigned)hi << 16);
  }
  uint4* dst = (uint4*)&texT[(size_t)p * 32];
  #pragma unroll
  for (int qq = 0; qq < 4; ++qq) {
    uint4 v; v.x = pk[qq * 4]; v.y = pk[qq * 4 + 1]; v.z = pk[qq * 4 + 2]; v.w = pk[qq * 4 + 3];
    dst[qq] = v;
  }
}

// Fused conv1(32->32,3x3,lrelu)+conv2(32->16,3x3) via MFMA 16x16x32 bf16.
// Block: batch b, 14x16 output tile. LDS: tex [20][18][32], inter [18][16][32],
// filters 13824 — all bf16, 69120 B -> 2 blocks/CU.
__global__ __launch_bounds__(256, 2) void conv_mfma(const ushort* __restrict__ texT,
                                                    const ushort* __restrict__ wbf,
                                                    float* __restrict__ out) {
  extern __shared__ ushort sm[];
  ushort* texs  = sm;            // 11520
  ushort* inter = sm + 11520;    // 9216
  ushort* fw    = sm + 20736;    // 13824
  const int tid = threadIdx.x;
  const int w = tid >> 6, lane = tid & 63;
  const int jn = lane & 15, q = lane >> 4;
  const int tx0 = blockIdx.x * TW, ty0 = blockIdx.y * TH, b = blockIdx.z;

  // filters -> LDS (already bf16, already [kpos][co][ci])
  const int4* wsrc = (const int4*)(wbf + (size_t)b * D_FLT);
  for (int i = tid; i < D_FLT / 8; i += 256) ((int4*)fw)[i] = wsrc[i];
  // tex tile -> LDS, zero-filled outside image
  for (int i = tid; i < 1440; i += 256) {
    int row = i / 72, c = i - row * 72;
    int px = c >> 2, part = c & 3;
    int gy = ty0 - 2 + row, gx = tx0 - 2 + px;
    int4 v; v.x = 0; v.y = 0; v.z = 0; v.w = 0;
    if (gy >= 0 && gy < 256 && gx >= 0 && gx < 256)
      v = ((const int4*)texT)[(gy * 256 + gx) * 4 + part];
    ((int4*)texs)[i] = v;
  }
  __syncthreads();

  // A-frags: lane holds row co=lane&15, k(ci)=(lane>>4)*8+0..7
  bf16x8 a0[9][2];
  #pragma unroll
  for (int kp = 0; kp < 9; ++kp)
    #pragma unroll
    for (int h = 0; h < 2; ++h)
      a0[kp][h] = *(const bf16x8*)&fw[(kp * 32 + h * 16 + jn) * 32 + q * 8];

  // conv1: inter rows r=0..17 (halo 1); wave w does rows w,w+4,...
  for (int r = w; r < 18; r += 4) {
    f32x4 acc0 = {0.f, 0.f, 0.f, 0.f}, acc1 = {0.f, 0.f, 0.f, 0.f};
    #pragma unroll
    for (int ky = 0; ky < 3; ++ky) {
      const ushort* trow = &texs[(r + ky) * 576 + q * 8];
      #pragma unroll
      for (int kx = 0; kx < 3; ++kx) {
        bf16x8 bf = *(const bf16x8*)&trow[(jn + kx) * 32];
        acc0 = __builtin_amdgcn_mfma_f32_16x16x32_bf16(a0[ky * 3 + kx][0], bf, acc0, 0, 0, 0);
        acc1 = __builtin_amdgcn_mfma_f32_16x16x32_bf16(a0[ky * 3 + kx][1], bf, acc1, 0, 0, 0);
      }
    }
    // D: col=lane&15 (pixel), row=(lane>>4)*4+reg (co). lrelu+cvt, write [y][x][co].
    // CRITICAL: positions outside the image must be EXACT ZERO (reference conv2
    // zero-pads; conv1 of halo positions adjacent to the border is nonzero).
    int gy1 = ty0 - 1 + r, gx1 = tx0 - 1 + jn;
    bool inimg = (gy1 >= 0 && gy1 < 256 && gx1 >= 0 && gx1 < 256);
    ushort4 p0, p1;
    p0.x = f2bf(lrelu(acc0[0])); p0.y = f2bf(lrelu(acc0[1]));
    p0.z = f2bf(lrelu(acc0[2])); p0.w = f2bf(lrelu(acc0[3]));
    p1.x = f2bf(lrelu(acc1[0])); p1.y = f2bf(lrelu(acc1[1]));
    p1.z = f2bf(lrelu(acc1[2])); p1.w = f2bf(lrelu(acc1[3]));
    if (!inimg) {
      p0.x = p0.y = p0.z = p0.w = 0;
      p1.x = p1.y = p1.z = p1.w = 0;
    }
    *(ushort4*)&inter[(r * 16 + jn) * 32 + q * 4] = p0;
    *(ushort4*)&inter[(r * 16 + jn) * 32 + 16 + q * 4] = p1;
  }

  bf16x8 a1[9];
  #pragma unroll
  for (int kp = 0; kp < 9; ++kp)
    a1[kp] = *(const bf16x8*)&fw[N0Q + (kp * 16 + jn) * 32 + q * 8];
  __syncthreads();

  // conv2: output rows ro=0..15; lanes jn>=TW compute garbage (reads spill into fw region,
  // still inside LDS) and are masked at the store.
  for (int ro = w; ro < 16; ro += 4) {
    f32x4 acc = {0.f, 0.f, 0.f, 0.f};
    #pragma unroll
    for (int ky = 0; ky < 3; ++ky) {
      const ushort* irow = &inter[(ro + ky) * 512 + q * 8];
      #pragma unroll
      for (int kx = 0; kx < 3; ++kx) {
        bf16x8 bf = *(const bf16x8*)&irow[(jn + kx) * 32];
        acc = __builtin_amdgcn_mfma_f32_16x16x32_bf16(a1[ky * 3 + kx], bf, acc, 0, 0, 0);
      }
    }
    int gx = tx0 + jn, gy = ty0 + ro;
    if (jn < TW && gx < 256) {
      #pragma unroll
      for (int ci = 0; ci < 4; ++ci) {
        int co = q * 4 + ci;
        out[(((size_t)b * 16 + co) * 256 + gy) * 256 + gx] = acc[ci];
      }
    }
  }
}

extern "C" void kernel_launch(void* const* d_in, const int* in_sizes, int n_in,
                              void* d_out, int out_size, void* d_ws, size_t ws_size,
                              hipStream_t stream) {
  const float* z   = (const float*)d_in[0];
  const float* tex = (const float*)d_in[1];
  const float* W1  = (const float*)d_in[2];
  const float* b1  = (const float*)d_in[3];
  const float* W2  = (const float*)d_in[4];
  const float* b2  = (const float*)d_in[5];
  const float* W3  = (const float*)d_in[6];
  const float* b3  = (const float*)d_in[7];
  float* out = (float*)d_out;

  // ws layout (bytes): h1 [0,32768) | h2 [32768,65536) | wbf bf16 [65536,507904) | texT bf16 [507904,4702208)
  float*  h1   = (float*)d_ws;
  float*  h2   = (float*)((char*)d_ws + 32768);
  ushort* wbf  = (ushort*)((char*)d_ws + 65536);
  ushort* texT = (ushort*)((char*)d_ws + 507904);

  fc_kernel<1024, true><<<2048, 256, 0, stream>>>(z, W1, b1, h1);
  fc_kernel<512,  true><<<2048, 256, 0, stream>>>(h1, W2, b2, h2);
  fc3_kernel<<<D_FLT / 4, 256, 0, stream>>>(h2, W3, b3, wbf);
  tex_to_bf16<<<256, 256, 0, stream>>>(tex, texT);

  dim3 grid((256 + TW - 1) / TW, 256 / TH, BATCH);
  conv_mfma<<<grid, 256, 34560 * sizeof(ushort), stream>>>(texT, wbf, out);
}

// Round 4
// 118.503 us; speedup vs baseline: 9.9301x; 1.0925x over previous
//
#include <hip/hip_runtime.h>
#include <hip/hip_bf16.h>

#define BATCH 16
#define D_OUT 1024
#define D_HID 512
#define D_FLT 13824
#define N0Q 9216
#define TW 14
#define TH 16

typedef __attribute__((ext_vector_type(8))) short bf16x8;
typedef __attribute__((ext_vector_type(4))) float f32x4;

__device__ __forceinline__ float lrelu(float x) { return x >= 0.f ? x : 0.2f * x; }
__device__ __forceinline__ ushort f2bf(float x) {
  unsigned u = __float_as_uint(x);
  u += 0x7FFFu + ((u >> 16) & 1u);
  return (ushort)(u >> 16);
}

// out[b][j] = act(sum_k in[b][k] * W[j][k] + bias[j]); one wave per output.
template<int K, bool ACT>
__global__ void fc_kernel(const float* __restrict__ in, const float* __restrict__ W,
                          const float* __restrict__ bias, float* __restrict__ out) {
  int wid = (blockIdx.x * blockDim.x + threadIdx.x) >> 6;
  int lane = threadIdx.x & 63;
  int b = wid >> 9;
  int j = wid & 511;
  float s = 0.f;
  for (int k = lane; k < K; k += 64) s += in[b * K + k] * W[j * K + k];
  #pragma unroll
  for (int off = 32; off; off >>= 1) s += __shfl_xor(s, off);
  if (lane == 0) {
    float v = s + bias[j];
    out[b * 512 + j] = ACT ? lrelu(v) : v;
  }
}

// fc3: wave per j, all 16 batches; writes bf16 filters PERMUTED to
// conv layout: flt0 -> [kpos][co32][ci32], flt1 -> 9216 + [kpos][co16][ci32].
__global__ void fc3_kernel(const float* __restrict__ h2, const float* __restrict__ W3,
                           const float* __restrict__ b3, ushort* __restrict__ wbf) {
  __shared__ float hs[BATCH * D_HID];
  int tid = threadIdx.x;
  for (int i = tid; i < BATCH * D_HID; i += 256) hs[i] = h2[i];
  __syncthreads();
  int w = tid >> 6, lane = tid & 63;
  int j = blockIdx.x * 4 + w;
  float acc[BATCH];
  #pragma unroll
  for (int b = 0; b < BATCH; ++b) acc[b] = 0.f;
  for (int k = lane; k < D_HID; k += 64) {
    float wv = W3[(size_t)j * D_HID + k];
    #pragma unroll
    for (int b = 0; b < BATCH; ++b) acc[b] += wv * hs[b * D_HID + k];
  }
  #pragma unroll
  for (int b = 0; b < BATCH; ++b) {
    #pragma unroll
    for (int off = 32; off; off >>= 1) acc[b] += __shfl_xor(acc[b], off);
  }
  if (lane == 0) {
    float bb = b3[j];
    int dst;
    if (j < N0Q) {
      int co = j / 288, rem = j - co * 288;
      int ci = rem / 9, kp = rem - ci * 9;
      dst = kp * 1024 + co * 32 + ci;
    } else {
      int t = j - N0Q;
      int co = t / 288, rem = t - co * 288;
      int ci = rem / 9, kp = rem - ci * 9;
      dst = N0Q + kp * 512 + co * 32 + ci;
    }
    #pragma unroll
    for (int b = 0; b < BATCH; ++b) wbf[(size_t)b * D_FLT + dst] = f2bf(acc[b] + bb);
  }
}

// tex fp32 [32][256][256] -> bf16 pixel-major [256*256][32]
__global__ void tex_to_bf16(const float* __restrict__ tex, ushort* __restrict__ texT) {
  int p = blockIdx.x * 256 + threadIdx.x;
  unsigned pk[16];
  #pragma unroll
  for (int i = 0; i < 16; ++i) {
    ushort lo = f2bf(tex[(2 * i) * 65536 + p]);
    ushort hi = f2bf(tex[(2 * i + 1) * 65536 + p]);
    pk[i] = (unsigned)lo | ((unsigned)hi << 16);
  }
  uint4* dst = (uint4*)&texT[(size_t)p * 32];
  #pragma unroll
  for (int qq = 0; qq < 4; ++qq) {
    uint4 v; v.x = pk[qq * 4]; v.y = pk[qq * 4 + 1]; v.z = pk[qq * 4 + 2]; v.w = pk[qq * 4 + 3];
    dst[qq] = v;
  }
}

// Fused conv1(32->32,3x3,lrelu)+conv2(32->16,3x3) via MFMA 16x16x32 bf16.
// LDS (all bf16, 40.75 KB -> 3 blocks/CU): tex [20 rows][18 px][32 ci] and
// inter [18][16][32], both with 16B-quad swizzle j' = (j + (p>>1)) & 3 inside
// each 64B pixel record -> every wave frag-read phase covers all 32 banks.
// A-fragments (filters) load straight from global (contiguous 1KB/wave, L2-hot).
__global__ __launch_bounds__(256, 3) void conv_mfma(const ushort* __restrict__ texT,
                                                    const ushort* __restrict__ wbf,
                                                    float* __restrict__ out) {
  extern __shared__ ushort sm[];
  ushort* texs  = sm;            // 11520 shorts
  ushort* inter = sm + 11520;    // 9216 + 128 pad
  const int tid = threadIdx.x;
  const int w = tid >> 6, lane = tid & 63;
  const int jn = lane & 15, q = lane >> 4;
  const int tx0 = blockIdx.x * TW, ty0 = blockIdx.y * TH, b = blockIdx.z;

  // A-frags from global: lane holds co = jn (+16h), ci = q*8..q*8+7
  const ushort* wb = wbf + (size_t)b * D_FLT;
  bf16x8 a0[9][2];
  #pragma unroll
  for (int kp = 0; kp < 9; ++kp)
    #pragma unroll
    for (int h = 0; h < 2; ++h)
      a0[kp][h] = *(const bf16x8*)&wb[(kp * 32 + h * 16 + jn) * 32 + q * 8];
  bf16x8 a1[9];
  #pragma unroll
  for (int kp = 0; kp < 9; ++kp)
    a1[kp] = *(const bf16x8*)&wb[N0Q + (kp * 16 + jn) * 32 + q * 8];

  // tex tile -> LDS (quad-swizzled), zero outside image
  for (int i = tid; i < 1440; i += 256) {
    int row = i / 72, c = i - row * 72;
    int px = c >> 2, j = c & 3;
    int gy = ty0 - 2 + row, gx = tx0 - 2 + px;
    int4 v; v.x = 0; v.y = 0; v.z = 0; v.w = 0;
    if (gy >= 0 && gy < 256 && gx >= 0 && gx < 256)
      v = ((const int4*)texT)[(gy * 256 + gx) * 4 + j];
    ((int4*)texs)[row * 72 + px * 4 + ((j + (px >> 1)) & 3)] = v;
  }
  __syncthreads();

  // conv1: inter rows r=0..17 (halo 1); wave w does rows w, w+4, ...
  for (int r = w; r < 18; r += 4) {
    f32x4 acc0 = {0.f, 0.f, 0.f, 0.f}, acc1 = {0.f, 0.f, 0.f, 0.f};
    #pragma unroll
    for (int ky = 0; ky < 3; ++ky) {
      const ushort* trow = &texs[(r + ky) * 576];
      #pragma unroll
      for (int kx = 0; kx < 3; ++kx) {
        int p = jn + kx;
        bf16x8 bf = *(const bf16x8*)&trow[p * 32 + ((q + (p >> 1)) & 3) * 8];
        acc0 = __builtin_amdgcn_mfma_f32_16x16x32_bf16(a0[ky * 3 + kx][0], bf, acc0, 0, 0, 0);
        acc1 = __builtin_amdgcn_mfma_f32_16x16x32_bf16(a0[ky * 3 + kx][1], bf, acc1, 0, 0, 0);
      }
    }
    // D: col=lane&15 (pixel), row=(lane>>4)*4+reg (co). Out-of-image inter
    // positions must be EXACT ZERO (reference conv2 zero-pads).
    int gy1 = ty0 - 1 + r, gx1 = tx0 - 1 + jn;
    bool inimg = (gy1 >= 0 && gy1 < 256 && gx1 >= 0 && gx1 < 256);
    ushort4 p0, p1;
    p0.x = f2bf(lrelu(acc0[0])); p0.y = f2bf(lrelu(acc0[1]));
    p0.z = f2bf(lrelu(acc0[2])); p0.w = f2bf(lrelu(acc0[3]));
    p1.x = f2bf(lrelu(acc1[0])); p1.y = f2bf(lrelu(acc1[1]));
    p1.z = f2bf(lrelu(acc1[2])); p1.w = f2bf(lrelu(acc1[3]));
    if (!inimg) {
      p0.x = p0.y = p0.z = p0.w = 0;
      p1.x = p1.y = p1.z = p1.w = 0;
    }
    int rec = r * 512 + jn * 32;
    int sub = (q & 1) * 4;
    *(ushort4*)&inter[rec + ((((q >> 1) + (jn >> 1)) & 3) * 8) + sub] = p0;      // co 4q..4q+3
    *(ushort4*)&inter[rec + (((2 + (q >> 1) + (jn >> 1)) & 3) * 8) + sub] = p1;  // co 16+4q..
  }
  __syncthreads();

  // conv2: output rows ro; lanes jn>=TW produce garbage (reads land in the
  // 128-short pad at worst) and are masked at the store.
  for (int ro = w; ro < 16; ro += 4) {
    f32x4 acc = {0.f, 0.f, 0.f, 0.f};
    #pragma unroll
    for (int ky = 0; ky < 3; ++ky) {
      const ushort* irow = &inter[(ro + ky) * 512];
      #pragma unroll
      for (int kx = 0; kx < 3; ++kx) {
        int p = jn + kx;
        bf16x8 bf = *(const bf16x8*)&irow[p * 32 + ((q + (p >> 1)) & 3) * 8];
        acc = __builtin_amdgcn_mfma_f32_16x16x32_bf16(a1[ky * 3 + kx], bf, acc, 0, 0, 0);
      }
    }
    int gx = tx0 + jn, gy = ty0 + ro;
    if (jn < TW && gx < 256) {
      #pragma unroll
      for (int ci = 0; ci < 4; ++ci) {
        int co = q * 4 + ci;
        out[(((size_t)b * 16 + co) * 256 + gy) * 256 + gx] = acc[ci];
      }
    }
  }
}

extern "C" void kernel_launch(void* const* d_in, const int* in_sizes, int n_in,
                              void* d_out, int out_size, void* d_ws, size_t ws_size,
                              hipStream_t stream) {
  const float* z   = (const float*)d_in[0];
  const float* tex = (const float*)d_in[1];
  const float* W1  = (const float*)d_in[2];
  const float* b1  = (const float*)d_in[3];
  const float* W2  = (const float*)d_in[4];
  const float* b2  = (const float*)d_in[5];
  const float* W3  = (const float*)d_in[6];
  const float* b3  = (const float*)d_in[7];
  float* out = (float*)d_out;

  // ws layout (bytes): h1 [0,32768) | h2 [32768,65536) | wbf bf16 [65536,507904) | texT bf16 [507904,4702208)
  float*  h1   = (float*)d_ws;
  float*  h2   = (float*)((char*)d_ws + 32768);
  ushort* wbf  = (ushort*)((char*)d_ws + 65536);
  ushort* texT = (ushort*)((char*)d_ws + 507904);

  fc_kernel<1024, true><<<2048, 256, 0, stream>>>(z, W1, b1, h1);
  fc_kernel<512,  true><<<2048, 256, 0, stream>>>(h1, W2, b2, h2);
  fc3_kernel<<<D_FLT / 4, 256, 0, stream>>>(h2, W3, b3, wbf);
  tex_to_bf16<<<256, 256, 0, stream>>>(tex, texT);

  dim3 grid((256 + TW - 1) / TW, 256 / TH, BATCH);
  conv_mfma<<<grid, 256, (11520 + 9216 + 128) * sizeof(ushort), stream>>>(texT, wbf, out);
}